// Round 4
// baseline (935.381 us; speedup 1.0000x reference)
//
#include <hip/hip_runtime.h>

#define D 128
#define DH 64      // uints per feature row (2 bf16 per uint)
#define BR 128     // rows per coarse bucket
#define NBMAX 512

typedef float f32x4 __attribute__((ext_vector_type(4)));
typedef short s16x8 __attribute__((ext_vector_type(8)));

static __device__ __forceinline__ unsigned short f2bf(float f) {
    unsigned u = __float_as_uint(f);
    u += 0x7FFF + ((u >> 16) & 1);   // RNE
    return (unsigned short)(u >> 16);
}
static __device__ __forceinline__ float bflo(unsigned u) { return __uint_as_float(u << 16); }
static __device__ __forceinline__ float bfhi(unsigned u) { return __uint_as_float(u & 0xFFFF0000u); }

// ---- pack x -> bf16 with (f, f+64) pairing: xh[row*64+j] = (bf16 x[row][j], bf16 x[row][j+64]) ----
__global__ void k_xpack(const float* __restrict__ x, unsigned* __restrict__ xh, int total) {
    int idx = blockIdx.x * 256 + threadIdx.x;
    if (idx >= total) return;
    int row = idx >> 6, j = idx & 63;
    float a = x[(size_t)row * D + j];
    float b = x[(size_t)row * D + 64 + j];
    xh[idx] = (unsigned)f2bf(a) | ((unsigned)f2bf(b) << 16);
}

// ---- coarse bucket histogram (LDS-staged) ----
__global__ __launch_bounds__(256)
void k_ccount(const int* __restrict__ rows, int* __restrict__ gcnt, int E, int nb) {
    __shared__ int h[NBMAX];
    int t = threadIdx.x;
    for (int i = t; i < nb; i += 256) h[i] = 0;
    __syncthreads();
    for (int e = blockIdx.x * 256 + t; e < E; e += gridDim.x * 256)
        atomicAdd(&h[rows[e] >> 7], 1);
    __syncthreads();
    for (int i = t; i < nb; i += 256)
        if (h[i]) atomicAdd(&gcnt[i], h[i]);
}

// ---- scan bucket counts -> cbase[0..nb], init cursors ----
__global__ __launch_bounds__(512)
void k_cscan(const int* __restrict__ gcnt, int* __restrict__ cbase,
             int* __restrict__ ccur, int nb) {
    __shared__ int s[512];
    int t = threadIdx.x;
    int v = (t < nb) ? gcnt[t] : 0;
    s[t] = v;
    __syncthreads();
    for (int d = 1; d < 512; d <<= 1) {
        int add = (t >= d) ? s[t - d] : 0;
        __syncthreads();
        s[t] += add;
        __syncthreads();
    }
    if (t < nb) {
        int excl = s[t] - v;
        cbase[t] = excl;
        ccur[t] = excl;
    }
    if (t == nb - 1) cbase[nb] = s[t];
}

// ---- coarse scatter: edges -> bucket-grouped sedge, LDS-staged for write locality ----
// sedge[p] = { col | (rowlocal<<16), bits(val) }   (col < 65536, rowlocal < 128)
__global__ __launch_bounds__(256)
void k_cscatter(const int* __restrict__ rows, const int* __restrict__ cols,
                const float* __restrict__ vals, int* __restrict__ ccur,
                uint2* __restrict__ sedge, int E, int nb, int chunk) {
    __shared__ int lcnt[NBMAX];
    __shared__ int lbase[NBMAX];
    int t = threadIdx.x;
    int c0 = blockIdx.x * chunk;
    int c1 = min(c0 + chunk, E);
    for (int i = t; i < nb; i += 256) lcnt[i] = 0;
    __syncthreads();
    for (int e = c0 + t; e < c1; e += 256)
        atomicAdd(&lcnt[rows[e] >> 7], 1);
    __syncthreads();
    for (int i = t; i < nb; i += 256) {
        int c = lcnt[i];
        lbase[i] = c ? atomicAdd(&ccur[i], c) : 0;
        lcnt[i] = 0;
    }
    __syncthreads();
    for (int e = c0 + t; e < c1; e += 256) {
        int r = rows[e];
        int b = r >> 7;
        int rk = atomicAdd(&lcnt[b], 1);
        uint2 ed;
        ed.x = (unsigned)cols[e] | ((unsigned)(r & (BR - 1)) << 16);
        ed.y = __float_as_uint(vals[e]);
        sedge[lbase[b] + rk] = ed;
    }
}

// ---- per-bucket aggregation: LDS fp32 accumulator [128 rows][128 feats] = 64 KB ----
// agg[row] = (1+eps)*x[row] + sum val*x[col];   output bf16 standard row-major packing
__global__ __launch_bounds__(512, 2)
void k_agg(const unsigned* __restrict__ xh, const float* __restrict__ x,
           const float* __restrict__ eps, const int* __restrict__ cbase,
           const uint2* __restrict__ sedge, unsigned* __restrict__ aggh, int N) {
    __shared__ float acc[BR * D];   // 64 KB
    int t = threadIdx.x, lane = t & 63, w = t >> 6;   // 8 waves
    for (int i = t; i < BR * D; i += 512) acc[i] = 0.f;
    __syncthreads();

    int b = blockIdx.x;
    int e0 = cbase[b], e1 = cbase[b + 1];
    int i = e0 + w * 4;
    for (; i + 4 <= e1; i += 32) {
        uint2 ed0 = sedge[i], ed1 = sedge[i + 1], ed2 = sedge[i + 2], ed3 = sedge[i + 3];
        unsigned u0 = xh[(size_t)(ed0.x & 0xFFFF) * DH + lane];
        unsigned u1 = xh[(size_t)(ed1.x & 0xFFFF) * DH + lane];
        unsigned u2 = xh[(size_t)(ed2.x & 0xFFFF) * DH + lane];
        unsigned u3 = xh[(size_t)(ed3.x & 0xFFFF) * DH + lane];
        float v0 = __uint_as_float(ed0.y), v1 = __uint_as_float(ed1.y);
        float v2 = __uint_as_float(ed2.y), v3 = __uint_as_float(ed3.y);
        int r0 = (ed0.x >> 16) * D, r1 = (ed1.x >> 16) * D;
        int r2 = (ed2.x >> 16) * D, r3 = (ed3.x >> 16) * D;
        atomicAdd(&acc[r0 + lane], v0 * bflo(u0));
        atomicAdd(&acc[r0 + 64 + lane], v0 * bfhi(u0));
        atomicAdd(&acc[r1 + lane], v1 * bflo(u1));
        atomicAdd(&acc[r1 + 64 + lane], v1 * bfhi(u1));
        atomicAdd(&acc[r2 + lane], v2 * bflo(u2));
        atomicAdd(&acc[r2 + 64 + lane], v2 * bfhi(u2));
        atomicAdd(&acc[r3 + lane], v3 * bflo(u3));
        atomicAdd(&acc[r3 + 64 + lane], v3 * bfhi(u3));
    }
    for (int j = i; j < e1; ++j) {
        uint2 ed = sedge[j];
        unsigned u = xh[(size_t)(ed.x & 0xFFFF) * DH + lane];
        float v = __uint_as_float(ed.y);
        int r = (ed.x >> 16) * D;
        atomicAdd(&acc[r + lane], v * bflo(u));
        atomicAdd(&acc[r + 64 + lane], v * bfhi(u));
    }
    __syncthreads();

    float s = 1.f + eps[0];
    int row0 = b * BR;
    for (int idx = t; idx < BR * DH; idx += 512) {
        int rl = idx >> 6, j = idx & 63;
        int grow = row0 + rl;
        if (grow < N) {
            float2 xv = *(const float2*)&x[(size_t)grow * D + j * 2];
            float a0 = acc[rl * D + j * 2]     + s * xv.x;
            float a1 = acc[rl * D + j * 2 + 1] + s * xv.y;
            aggh[(size_t)grow * DH + j] = (unsigned)f2bf(a0) | ((unsigned)f2bf(a1) << 16);
        }
    }
}

// ---- pre-swizzle W (fp32 128x128) into 16x16x32 MFMA B-fragment layout, bf16 ----
__global__ void k_prepw(const float* __restrict__ W, unsigned short* __restrict__ Wsw) {
    int idx = blockIdx.x * 256 + threadIdx.x;   // 0..2047
    if (idx >= 2048) return;
    int lane = idx & 63, nt = (idx >> 6) & 7, kt = idx >> 9;
    int k0 = kt * 32 + (lane >> 4) * 8;
    int n = nt * 16 + (lane & 15);
    unsigned short* dst = &Wsw[(size_t)((kt * 8 + nt) * 64 + lane) * 8];
#pragma unroll
    for (int j = 0; j < 8; ++j) dst[j] = f2bf(W[(k0 + j) * D + n]);
}

// ---- MFMA GEMM + fused batch-stat partials (A bf16 standard row-major packing) ----
__global__ __launch_bounds__(256)
void k_gemm(const unsigned short* __restrict__ A, const unsigned short* __restrict__ Wsw,
            const float* __restrict__ bias, unsigned short* __restrict__ Hout,
            float* __restrict__ stats, int N) {
    __shared__ float redS[4 * D];
    __shared__ float redQ[4 * D];
    int tid = threadIdx.x, lane = tid & 63, w = tid >> 6;
    int row0 = blockIdx.x * 64 + w * 16;
    int m = lane & 15, quad = lane >> 4;

    f32x4 acc[8];
#pragma unroll
    for (int nt = 0; nt < 8; ++nt) acc[nt] = (f32x4){0.f, 0.f, 0.f, 0.f};

    int arow = row0 + m;
    bool avalid = arow < N;
    const s16x8* wp = (const s16x8*)Wsw;
    s16x8 az = {0, 0, 0, 0, 0, 0, 0, 0};
#pragma unroll
    for (int kt = 0; kt < 4; ++kt) {
        s16x8 a = avalid ? *(const s16x8*)&A[(size_t)arow * D + kt * 32 + quad * 8] : az;
#pragma unroll
        for (int nt = 0; nt < 8; ++nt) {
            s16x8 b = wp[(kt * 8 + nt) * 64 + lane];
            acc[nt] = __builtin_amdgcn_mfma_f32_16x16x32_bf16(a, b, acc[nt], 0, 0, 0);
        }
    }

#pragma unroll
    for (int nt = 0; nt < 8; ++nt) {
        float bv = bias[nt * 16 + m];
        float s = 0.f, q = 0.f;
#pragma unroll
        for (int r = 0; r < 4; ++r) {
            int row = row0 + quad * 4 + r;
            float h = acc[nt][r] + bv;
            if (row < N) {
                Hout[(size_t)row * D + nt * 16 + m] = f2bf(h);
                s += h; q += h * h;
            }
        }
        s += __shfl_xor(s, 16, 64); s += __shfl_xor(s, 32, 64);
        q += __shfl_xor(q, 16, 64); q += __shfl_xor(q, 32, 64);
        if (quad == 0) {
            redS[w * D + nt * 16 + m] = s;
            redQ[w * D + nt * 16 + m] = q;
        }
    }
    __syncthreads();
    if (tid < D) {
        float ts = redS[tid] + redS[D + tid] + redS[2 * D + tid] + redS[3 * D + tid];
        float tq = redQ[tid] + redQ[D + tid] + redQ[2 * D + tid] + redQ[3 * D + tid];
        atomicAdd(&stats[tid], ts);
        atomicAdd(&stats[D + tid], tq);
    }
}

// ---- finalize: (sum,sumsq) -> fused (scale, shift) ----
__global__ void k_stats(float* __restrict__ stats, const float* __restrict__ g,
                        const float* __restrict__ be, float invN) {
    int j = threadIdx.x;
    float mean = stats[j] * invN;
    float var = stats[D + j] * invN - mean * mean;
    var = fmaxf(var, 0.f);
    float inv = rsqrtf(var + 1e-5f);
    float a = g[j] * inv;
    float b = be[j] - mean * a;
    stats[j] = a;
    stats[D + j] = b;
}

// ---- BN + swish on bf16 input; out bf16 (layer1) or fp32 (final) ----
template <bool F32OUT>
__global__ void k_bnswish(const unsigned* __restrict__ inh, void* __restrict__ outp,
                          const float* __restrict__ stats, int total4) {
    __shared__ float sa[D], sb[D];
    if (threadIdx.x < D) {
        sa[threadIdx.x] = stats[threadIdx.x];
        sb[threadIdx.x] = stats[D + threadIdx.x];
    }
    __syncthreads();
    int i = blockIdx.x * blockDim.x + threadIdx.x;
    if (i >= total4) return;
    uint2 u = ((const uint2*)inh)[i];
    int c = (i * 4) & (D - 1);
    float d0 = bflo(u.x) * sa[c + 0] + sb[c + 0];
    float d1 = bfhi(u.x) * sa[c + 1] + sb[c + 1];
    float d2 = bflo(u.y) * sa[c + 2] + sb[c + 2];
    float d3 = bfhi(u.y) * sa[c + 3] + sb[c + 3];
    float o0 = d0 / (1.f + __expf(-d0));
    float o1 = d1 / (1.f + __expf(-d1));
    float o2 = d2 / (1.f + __expf(-d2));
    float o3 = d3 / (1.f + __expf(-d3));
    if (F32OUT) {
        ((float4*)outp)[i] = make_float4(o0, o1, o2, o3);
    } else {
        uint2 o;
        o.x = (unsigned)f2bf(o0) | ((unsigned)f2bf(o1) << 16);
        o.y = (unsigned)f2bf(o2) | ((unsigned)f2bf(o3) << 16);
        ((uint2*)outp)[i] = o;
    }
}

extern "C" void kernel_launch(void* const* d_in, const int* in_sizes, int n_in,
                              void* d_out, int out_size, void* d_ws, size_t ws_size,
                              hipStream_t stream) {
    const float* x    = (const float*)d_in[0];
    const float* vals = (const float*)d_in[1];
    const float* W1   = (const float*)d_in[2];
    const float* b1   = (const float*)d_in[3];
    const float* g1   = (const float*)d_in[4];
    const float* be1  = (const float*)d_in[5];
    const float* W2   = (const float*)d_in[6];
    const float* b2   = (const float*)d_in[7];
    const float* g2   = (const float*)d_in[8];
    const float* be2  = (const float*)d_in[9];
    const float* eps  = (const float*)d_in[10];
    const int*  rows  = (const int*)d_in[11];
    const int*  cols  = (const int*)d_in[12];
    float* out = (float*)d_out;

    int N = in_sizes[0] / D;
    int E = in_sizes[1];
    int nb = (N + BR - 1) / BR;      // 391 coarse buckets

    // ---- workspace layout ----
    char* p = (char*)d_ws;
    float* stats = (float*)p;              p += 2 * D * sizeof(float);
    int* ccnt = (int*)p;                   p += (size_t)NBMAX * sizeof(int);
    int* cbase = (int*)p;                  p += (size_t)(NBMAX + 1) * sizeof(int);
    int* ccur = (int*)p;                   p += (size_t)NBMAX * sizeof(int);
    p = (char*)(((uintptr_t)p + 15) & ~(uintptr_t)15);
    unsigned short* Wsw1 = (unsigned short*)p; p += (size_t)D * D * 2;
    unsigned short* Wsw2 = (unsigned short*)p; p += (size_t)D * D * 2;
    p = (char*)(((uintptr_t)p + 15) & ~(uintptr_t)15);
    uint2* sedge = (uint2*)p;              p += (size_t)E * sizeof(uint2);
    unsigned* xh = (unsigned*)p;           p += (size_t)N * DH * sizeof(unsigned);  // also H buffer
    unsigned* aggh = (unsigned*)p;         /* N*DH uints */

    int total4 = N * D / 4;
    int eb = (total4 + 255) / 256;
    int gblk = (N + 63) / 64;
    int chunk = (E + 255) / 256;
    float invN = 1.0f / (float)N;

    // ---- x -> paired bf16; W -> swizzled bf16 frags ----
    k_xpack<<<(N * DH + 255) / 256, 256, 0, stream>>>(x, xh, N * DH);
    k_prepw<<<8, 256, 0, stream>>>(W1, Wsw1);
    k_prepw<<<8, 256, 0, stream>>>(W2, Wsw2);

    // ---- coarse bucket sort of edges ----
    hipMemsetAsync(ccnt, 0, (size_t)NBMAX * sizeof(int), stream);
    k_ccount<<<256, 256, 0, stream>>>(rows, ccnt, E, nb);
    k_cscan<<<1, 512, 0, stream>>>(ccnt, cbase, ccur, nb);
    k_cscatter<<<256, 256, 0, stream>>>(rows, cols, vals, ccur, sedge, E, nb, chunk);

    // ---- per-bucket LDS aggregation ----
    k_agg<<<nb, 512, 0, stream>>>(xh, x, eps, cbase, sedge, aggh, N);

    // ---- layer 1: MFMA GEMM -> stats -> BN+swish (bf16 out into aggh) ----
    hipMemsetAsync(stats, 0, 2 * D * sizeof(float), stream);
    k_gemm<<<gblk, 256, 0, stream>>>((const unsigned short*)aggh, Wsw1, b1,
                                     (unsigned short*)xh, stats, N);
    k_stats<<<1, D, 0, stream>>>(stats, g1, be1, invN);
    k_bnswish<false><<<eb, 256, 0, stream>>>(xh, aggh, stats, total4);

    // ---- layer 2: MFMA GEMM -> stats -> BN+swish (fp32 out) ----
    hipMemsetAsync(stats, 0, 2 * D * sizeof(float), stream);
    k_gemm<<<gblk, 256, 0, stream>>>((const unsigned short*)aggh, Wsw2, b2,
                                     (unsigned short*)xh, stats, N);
    k_stats<<<1, D, 0, stream>>>(stats, g2, be2, invN);
    k_bnswish<true><<<eb, 256, 0, stream>>>(xh, out, stats, total4);
}

// Round 5
// 270.109 us; speedup vs baseline: 3.4630x; 3.4630x over previous
//
#include <hip/hip_runtime.h>

#define D 128
#define DH 64      // uints per feature row (2 bf16 per uint)
#define BR 128     // rows per coarse bucket
#define NBMAX 512
#define FCAP 4096  // max edges per bucket staged in LDS (exp ~2048, uniform rows)

typedef float f32x4 __attribute__((ext_vector_type(4)));
typedef short s16x8 __attribute__((ext_vector_type(8)));

static __device__ __forceinline__ unsigned short f2bf(float f) {
    unsigned u = __float_as_uint(f);
    u += 0x7FFF + ((u >> 16) & 1);   // RNE
    return (unsigned short)(u >> 16);
}
static __device__ __forceinline__ float bflo(unsigned u) { return __uint_as_float(u << 16); }
static __device__ __forceinline__ float bfhi(unsigned u) { return __uint_as_float(u & 0xFFFF0000u); }

// ---- convert x (fp32) -> packed bf16, standard row-major ----
__global__ void k_xpack(const float* __restrict__ x, unsigned* __restrict__ xh, int total4) {
    int i = blockIdx.x * blockDim.x + threadIdx.x;
    if (i >= total4) return;
    float4 v = ((const float4*)x)[i];
    uint2 o;
    o.x = (unsigned)f2bf(v.x) | ((unsigned)f2bf(v.y) << 16);
    o.y = (unsigned)f2bf(v.z) | ((unsigned)f2bf(v.w) << 16);
    ((uint2*)xh)[i] = o;
}

// ---- pre-swizzle W1,W2 into 16x16x32 MFMA B-frag layout, bf16 (one launch, 2 weights) ----
__global__ void k_prepw(const float* __restrict__ W1, const float* __restrict__ W2,
                        unsigned short* __restrict__ Wsw1, unsigned short* __restrict__ Wsw2) {
    int gidx = blockIdx.x * 256 + threadIdx.x;   // 0..4095
    const float* W = (gidx < 2048) ? W1 : W2;
    unsigned short* Wsw = (gidx < 2048) ? Wsw1 : Wsw2;
    int idx = gidx & 2047;
    int lane = idx & 63, nt = (idx >> 6) & 7, kt = idx >> 9;
    int k0 = kt * 32 + (lane >> 4) * 8;
    int n = nt * 16 + (lane & 15);
    unsigned short* dst = &Wsw[(size_t)((kt * 8 + nt) * 64 + lane) * 8];
#pragma unroll
    for (int j = 0; j < 8; ++j) dst[j] = f2bf(W[(k0 + j) * D + n]);
}

// ---- coarse bucket histogram (LDS-staged) ----
__global__ __launch_bounds__(256)
void k_ccount(const int* __restrict__ rows, int* __restrict__ gcnt, int E, int nb) {
    __shared__ int h[NBMAX];
    int t = threadIdx.x;
    for (int i = t; i < nb; i += 256) h[i] = 0;
    __syncthreads();
    for (int e = blockIdx.x * 256 + t; e < E; e += gridDim.x * 256)
        atomicAdd(&h[rows[e] >> 7], 1);
    __syncthreads();
    for (int i = t; i < nb; i += 256)
        if (h[i]) atomicAdd(&gcnt[i], h[i]);
}

// ---- scan bucket counts -> cbase[0..nb], init cursors ----
__global__ __launch_bounds__(512)
void k_cscan(const int* __restrict__ gcnt, int* __restrict__ cbase,
             int* __restrict__ ccur, int nb) {
    __shared__ int s[512];
    int t = threadIdx.x;
    int v = (t < nb) ? gcnt[t] : 0;
    s[t] = v;
    __syncthreads();
    for (int d = 1; d < 512; d <<= 1) {
        int add = (t >= d) ? s[t - d] : 0;
        __syncthreads();
        s[t] += add;
        __syncthreads();
    }
    if (t < nb) {
        int excl = s[t] - v;
        cbase[t] = excl;
        ccur[t] = excl;
    }
    if (t == nb - 1) cbase[nb] = s[t];
}

// ---- coarse scatter: edges -> bucket-grouped sedge, LDS-staged for write locality ----
// sedge[p] = { col | (rowlocal<<16), bits(val) }
__global__ __launch_bounds__(256)
void k_cscatter(const int* __restrict__ rows, const int* __restrict__ cols,
                const float* __restrict__ vals, int* __restrict__ ccur,
                uint2* __restrict__ sedge, int E, int nb, int chunk) {
    __shared__ int lcnt[NBMAX];
    __shared__ int lbase[NBMAX];
    int t = threadIdx.x;
    int c0 = blockIdx.x * chunk;
    int c1 = min(c0 + chunk, E);
    for (int i = t; i < nb; i += 256) lcnt[i] = 0;
    __syncthreads();
    for (int e = c0 + t; e < c1; e += 256)
        atomicAdd(&lcnt[rows[e] >> 7], 1);
    __syncthreads();
    for (int i = t; i < nb; i += 256) {
        int c = lcnt[i];
        lbase[i] = c ? atomicAdd(&ccur[i], c) : 0;
        lcnt[i] = 0;
    }
    __syncthreads();
    for (int e = c0 + t; e < c1; e += 256) {
        int r = rows[e];
        int b = r >> 7;
        int rk = atomicAdd(&lcnt[b], 1);
        uint2 ed;
        ed.x = (unsigned)cols[e] | ((unsigned)(r & (BR - 1)) << 16);
        ed.y = __float_as_uint(vals[e]);
        sedge[lbase[b] + rk] = ed;
    }
}

// ---- per-bucket fine CSR sort in LDS: coarse sedge -> row-sorted sedge2 + noff ----
__global__ __launch_bounds__(256)
void k_fine(const uint2* __restrict__ sedge, const int* __restrict__ cbase,
            uint2* __restrict__ sedge2, int* __restrict__ noff, int N, int nb) {
    __shared__ int cnt[BR], sbase[BR], cur[BR];
    __shared__ uint2 ebuf[FCAP];
    int b = blockIdx.x, t = threadIdx.x;
    int e0 = cbase[b], e1 = cbase[b + 1];
    int cntE = e1 - e0;
    if (t < BR) { cnt[t] = 0; cur[t] = 0; }
    __syncthreads();
    for (int e = e0 + t; e < e1; e += 256)
        atomicAdd(&cnt[sedge[e].x >> 16], 1);
    __syncthreads();
    if (t < BR) sbase[t] = cnt[t];
    __syncthreads();
    for (int d = 1; d < BR; d <<= 1) {
        int add = (t < BR && t >= d) ? sbase[t - d] : 0;
        __syncthreads();
        if (t < BR) sbase[t] += add;
        __syncthreads();
    }
    int row0 = b * BR;
    if (t < BR) {
        int ex = sbase[t] - cnt[t];    // exclusive prefix
        sbase[t] = ex;
        if (row0 + t < N) noff[row0 + t] = e0 + ex;
    }
    if (b == nb - 1 && t == 0) noff[N] = e1;
    __syncthreads();
    if (cntE <= FCAP) {
        for (int e = e0 + t; e < e1; e += 256) {
            uint2 ed = sedge[e];
            int r = ed.x >> 16;
            int p = sbase[r] + atomicAdd(&cur[r], 1);
            ebuf[p] = make_uint2(ed.x & 0xFFFFu, ed.y);
        }
        __syncthreads();
        for (int i = t; i < cntE; i += 256)
            sedge2[e0 + i] = ebuf[i];
    } else {  // fallback (statistically never for uniform rows)
        for (int e = e0 + t; e < e1; e += 256) {
            uint2 ed = sedge[e];
            int r = ed.x >> 16;
            int p = e0 + sbase[r] + atomicAdd(&cur[r], 1);
            sedge2[p] = make_uint2(ed.x & 0xFFFFu, ed.y);
        }
    }
}

// ---- segment-sum gather (bf16 rows, fp32 accumulate, x4 unroll) ----
__global__ __launch_bounds__(256)
void k_gather(const unsigned* __restrict__ xh, const float* __restrict__ eps,
              const int* __restrict__ off, const uint2* __restrict__ sedge,
              unsigned* __restrict__ aggh, int N) {
    int node = blockIdx.x * 4 + (threadIdx.x >> 6);
    int lane = threadIdx.x & 63;
    if (node >= N) return;
    float s = 1.0f + eps[0];
    unsigned u = xh[(size_t)node * DH + lane];
    float ax = s * bflo(u), ay = s * bfhi(u);
    int b = off[node], e = off[node + 1];
    int i = b;
    for (; i + 4 <= e; i += 4) {
        uint2 e0 = sedge[i], e1 = sedge[i + 1], e2 = sedge[i + 2], e3 = sedge[i + 3];
        unsigned u0 = xh[(size_t)e0.x * DH + lane];
        unsigned u1 = xh[(size_t)e1.x * DH + lane];
        unsigned u2 = xh[(size_t)e2.x * DH + lane];
        unsigned u3 = xh[(size_t)e3.x * DH + lane];
        float v0 = __uint_as_float(e0.y), v1 = __uint_as_float(e1.y);
        float v2 = __uint_as_float(e2.y), v3 = __uint_as_float(e3.y);
        ax += v0 * bflo(u0) + v1 * bflo(u1) + v2 * bflo(u2) + v3 * bflo(u3);
        ay += v0 * bfhi(u0) + v1 * bfhi(u1) + v2 * bfhi(u2) + v3 * bfhi(u3);
    }
    for (; i < e; ++i) {
        uint2 ed = sedge[i];
        unsigned uu = xh[(size_t)ed.x * DH + lane];
        float v = __uint_as_float(ed.y);
        ax += v * bflo(uu);
        ay += v * bfhi(uu);
    }
    aggh[(size_t)node * DH + lane] = (unsigned)f2bf(ax) | ((unsigned)f2bf(ay) << 16);
}

// ---- MFMA GEMM + fused batch-stat partials ----
__global__ __launch_bounds__(256)
void k_gemm(const unsigned short* __restrict__ A, const unsigned short* __restrict__ Wsw,
            const float* __restrict__ bias, unsigned short* __restrict__ Hout,
            float* __restrict__ stats, int N) {
    __shared__ float redS[4 * D];
    __shared__ float redQ[4 * D];
    int tid = threadIdx.x, lane = tid & 63, w = tid >> 6;
    int row0 = blockIdx.x * 64 + w * 16;
    int m = lane & 15, quad = lane >> 4;

    f32x4 acc[8];
#pragma unroll
    for (int nt = 0; nt < 8; ++nt) acc[nt] = (f32x4){0.f, 0.f, 0.f, 0.f};

    int arow = row0 + m;
    bool avalid = arow < N;
    const s16x8* wp = (const s16x8*)Wsw;
    s16x8 az = {0, 0, 0, 0, 0, 0, 0, 0};
#pragma unroll
    for (int kt = 0; kt < 4; ++kt) {
        s16x8 a = avalid ? *(const s16x8*)&A[(size_t)arow * D + kt * 32 + quad * 8] : az;
#pragma unroll
        for (int nt = 0; nt < 8; ++nt) {
            s16x8 b = wp[(kt * 8 + nt) * 64 + lane];
            acc[nt] = __builtin_amdgcn_mfma_f32_16x16x32_bf16(a, b, acc[nt], 0, 0, 0);
        }
    }

#pragma unroll
    for (int nt = 0; nt < 8; ++nt) {
        float bv = bias[nt * 16 + m];
        float s = 0.f, q = 0.f;
#pragma unroll
        for (int r = 0; r < 4; ++r) {
            int row = row0 + quad * 4 + r;
            float h = acc[nt][r] + bv;
            if (row < N) {
                Hout[(size_t)row * D + nt * 16 + m] = f2bf(h);
                s += h; q += h * h;
            }
        }
        s += __shfl_xor(s, 16, 64); s += __shfl_xor(s, 32, 64);
        q += __shfl_xor(q, 16, 64); q += __shfl_xor(q, 32, 64);
        if (quad == 0) {
            redS[w * D + nt * 16 + m] = s;
            redQ[w * D + nt * 16 + m] = q;
        }
    }
    __syncthreads();
    if (tid < D) {
        float ts = redS[tid] + redS[D + tid] + redS[2 * D + tid] + redS[3 * D + tid];
        float tq = redQ[tid] + redQ[D + tid] + redQ[2 * D + tid] + redQ[3 * D + tid];
        atomicAdd(&stats[tid], ts);
        atomicAdd(&stats[D + tid], tq);
    }
}

// ---- BN + swish, finalize fused (raw sums -> scale/shift in preamble) ----
template <bool F32OUT>
__global__ void k_bnswish(const unsigned* __restrict__ inh, void* __restrict__ outp,
                          const float* __restrict__ stats, const float* __restrict__ g,
                          const float* __restrict__ be, float invN, int total4) {
    __shared__ float sa[D], sb[D];
    int j = threadIdx.x;
    if (j < D) {
        float mean = stats[j] * invN;
        float var = fmaxf(stats[D + j] * invN - mean * mean, 0.f);
        float a = g[j] * rsqrtf(var + 1e-5f);
        sa[j] = a;
        sb[j] = be[j] - mean * a;
    }
    __syncthreads();
    int i = blockIdx.x * blockDim.x + threadIdx.x;
    if (i >= total4) return;
    uint2 u = ((const uint2*)inh)[i];
    int c = (i * 4) & (D - 1);
    float d0 = bflo(u.x) * sa[c + 0] + sb[c + 0];
    float d1 = bfhi(u.x) * sa[c + 1] + sb[c + 1];
    float d2 = bflo(u.y) * sa[c + 2] + sb[c + 2];
    float d3 = bfhi(u.y) * sa[c + 3] + sb[c + 3];
    float o0 = d0 / (1.f + __expf(-d0));
    float o1 = d1 / (1.f + __expf(-d1));
    float o2 = d2 / (1.f + __expf(-d2));
    float o3 = d3 / (1.f + __expf(-d3));
    if (F32OUT) {
        ((float4*)outp)[i] = make_float4(o0, o1, o2, o3);
    } else {
        uint2 o;
        o.x = (unsigned)f2bf(o0) | ((unsigned)f2bf(o1) << 16);
        o.y = (unsigned)f2bf(o2) | ((unsigned)f2bf(o3) << 16);
        ((uint2*)outp)[i] = o;
    }
}

extern "C" void kernel_launch(void* const* d_in, const int* in_sizes, int n_in,
                              void* d_out, int out_size, void* d_ws, size_t ws_size,
                              hipStream_t stream) {
    const float* x    = (const float*)d_in[0];
    const float* vals = (const float*)d_in[1];
    const float* W1   = (const float*)d_in[2];
    const float* b1   = (const float*)d_in[3];
    const float* g1   = (const float*)d_in[4];
    const float* be1  = (const float*)d_in[5];
    const float* W2   = (const float*)d_in[6];
    const float* b2   = (const float*)d_in[7];
    const float* g2   = (const float*)d_in[8];
    const float* be2  = (const float*)d_in[9];
    const float* eps  = (const float*)d_in[10];
    const int*  rows  = (const int*)d_in[11];
    const int*  cols  = (const int*)d_in[12];
    float* out = (float*)d_out;

    int N = in_sizes[0] / D;
    int E = in_sizes[1];
    int nb = (N + BR - 1) / BR;

    // ---- workspace layout ----
    char* p = (char*)d_ws;
    float* stats = (float*)p;              p += 4 * D * sizeof(float);   // stats1 | stats2
    int* ccnt = (int*)p;                   p += (size_t)NBMAX * sizeof(int);
    int* cbase = (int*)p;                  p += (size_t)(NBMAX + 1) * sizeof(int);
    int* ccur = (int*)p;                   p += (size_t)NBMAX * sizeof(int);
    int* noff = (int*)p;                   p += (size_t)(N + 2) * sizeof(int);
    p = (char*)(((uintptr_t)p + 15) & ~(uintptr_t)15);
    unsigned short* Wsw1 = (unsigned short*)p; p += (size_t)D * D * 2;
    unsigned short* Wsw2 = (unsigned short*)p; p += (size_t)D * D * 2;
    p = (char*)(((uintptr_t)p + 15) & ~(uintptr_t)15);
    uint2* sedge  = (uint2*)p;             p += (size_t)E * sizeof(uint2);
    uint2* sedge2 = (uint2*)p;             p += (size_t)E * sizeof(uint2);
    unsigned* xh = (unsigned*)p;           p += (size_t)N * DH * sizeof(unsigned);  // also H buffer
    unsigned* aggh = (unsigned*)p;         /* N*DH uints */

    float* stats1 = stats;
    float* stats2 = stats + 2 * D;

    int total4 = N * D / 4;
    int eb = (total4 + 255) / 256;
    int gblk = (N + 63) / 64;
    int chunk = (E + 255) / 256;
    float invN = 1.0f / (float)N;

    // ---- precompute: bf16 x, swizzled weights; zero stats ----
    k_xpack<<<eb, 256, 0, stream>>>(x, xh, total4);
    k_prepw<<<16, 256, 0, stream>>>(W1, W2, Wsw1, Wsw2);
    hipMemsetAsync(stats, 0, 4 * D * sizeof(float), stream);

    // ---- CSR build: coarse buckets then per-bucket fine sort ----
    hipMemsetAsync(ccnt, 0, (size_t)NBMAX * sizeof(int), stream);
    k_ccount<<<256, 256, 0, stream>>>(rows, ccnt, E, nb);
    k_cscan<<<1, 512, 0, stream>>>(ccnt, cbase, ccur, nb);
    k_cscatter<<<256, 256, 0, stream>>>(rows, cols, vals, ccur, sedge, E, nb, chunk);
    k_fine<<<nb, 256, 0, stream>>>(sedge, cbase, sedge2, noff, N, nb);

    // ---- gather ----
    k_gather<<<(N + 3) / 4, 256, 0, stream>>>(xh, eps, noff, sedge2, aggh, N);

    // ---- layer 1 ----
    k_gemm<<<gblk, 256, 0, stream>>>((const unsigned short*)aggh, Wsw1, b1,
                                     (unsigned short*)xh, stats1, N);
    k_bnswish<false><<<eb, 256, 0, stream>>>(xh, aggh, stats1, g1, be1, invN, total4);

    // ---- layer 2 ----
    k_gemm<<<gblk, 256, 0, stream>>>((const unsigned short*)aggh, Wsw2, b2,
                                     (unsigned short*)xh, stats2, N);
    k_bnswish<true><<<eb, 256, 0, stream>>>(xh, out, stats2, g2, be2, invN, total4);
}

// Round 6
// 267.955 us; speedup vs baseline: 3.4908x; 1.0080x over previous
//
#include <hip/hip_runtime.h>

#define D 128
#define DH 64      // uints per feature row (2 bf16 per uint)
#define BR 128     // rows per coarse bucket
#define NBMAX 512
#define HB 64      // histogram partial blocks
#define FCAP 4096  // max edges per bucket staged in LDS (exp ~2046 +- 45)

typedef float f32x4 __attribute__((ext_vector_type(4)));
typedef short s16x8 __attribute__((ext_vector_type(8)));

static __device__ __forceinline__ unsigned short f2bf(float f) {
    unsigned u = __float_as_uint(f);
    u += 0x7FFF + ((u >> 16) & 1);   // RNE
    return (unsigned short)(u >> 16);
}
static __device__ __forceinline__ float bflo(unsigned u) { return __uint_as_float(u << 16); }
static __device__ __forceinline__ float bfhi(unsigned u) { return __uint_as_float(u & 0xFFFF0000u); }
static __device__ __forceinline__ float bf2f(short v) {
    return __uint_as_float(((unsigned)(unsigned short)v) << 16);
}

// ---- fused setup: [0,eb) xpack | [eb,eb+HB) row histogram partials | [eb+HB,+16) prepw ----
__global__ __launch_bounds__(256)
void k_setup(const float* __restrict__ x, unsigned* __restrict__ xh, int total4,
             const int* __restrict__ rows, int* __restrict__ gpart, int E,
             const float* __restrict__ W1, const float* __restrict__ W2,
             unsigned short* __restrict__ Wsw1, unsigned short* __restrict__ Wsw2,
             int eb, int nb) {
    __shared__ int h[NBMAX];
    int bid = blockIdx.x, t = threadIdx.x;
    if (bid < eb) {
        int i = bid * 256 + t;
        if (i < total4) {
            float4 v = ((const float4*)x)[i];
            uint2 o;
            o.x = (unsigned)f2bf(v.x) | ((unsigned)f2bf(v.y) << 16);
            o.y = (unsigned)f2bf(v.z) | ((unsigned)f2bf(v.w) << 16);
            ((uint2*)xh)[i] = o;
        }
    } else if (bid < eb + HB) {
        int hb = bid - eb;
        for (int i = t; i < nb; i += 256) h[i] = 0;
        __syncthreads();
        int chunk = (E + HB - 1) / HB;
        int e0 = hb * chunk, e1 = min(e0 + chunk, E);
        for (int e = e0 + t; e < e1; e += 256)
            atomicAdd(&h[rows[e] >> 7], 1);
        __syncthreads();
        for (int i = t; i < nb; i += 256) gpart[hb * NBMAX + i] = h[i];
    } else {
        int gidx = (bid - eb - HB) * 256 + t;   // 0..4095
        const float* W = (gidx < 2048) ? W1 : W2;
        unsigned short* Wsw = (gidx < 2048) ? Wsw1 : Wsw2;
        int idx = gidx & 2047;
        int lane = idx & 63, nt = (idx >> 6) & 7, kt = idx >> 9;
        int k0 = kt * 32 + (lane >> 4) * 8;
        int n = nt * 16 + (lane & 15);
        unsigned short* dst = &Wsw[(size_t)((kt * 8 + nt) * 64 + lane) * 8];
#pragma unroll
        for (int j = 0; j < 8; ++j) dst[j] = f2bf(W[(k0 + j) * D + n]);
    }
}

// ---- reduce histogram partials, scan -> cbase/ccur; zero stats (512 floats) ----
__global__ __launch_bounds__(512)
void k_cscan(const int* __restrict__ gpart, int* __restrict__ cbase,
             int* __restrict__ ccur, float* __restrict__ stats, int nb) {
    __shared__ int s[512];
    int t = threadIdx.x;
    int v = 0;
    if (t < nb)
        for (int hb = 0; hb < HB; ++hb) v += gpart[hb * NBMAX + t];
    s[t] = v;
    __syncthreads();
    for (int d = 1; d < 512; d <<= 1) {
        int add = (t >= d) ? s[t - d] : 0;
        __syncthreads();
        s[t] += add;
        __syncthreads();
    }
    if (t < nb) {
        int excl = s[t] - v;
        cbase[t] = excl;
        ccur[t] = excl;
    }
    if (t == nb - 1) cbase[nb] = s[t];
    stats[t] = 0.f;   // 4*D = 512 floats: stats1 | stats2
}

// ---- coarse scatter: edges -> bucket-grouped sedge, LDS-staged for write locality ----
__global__ __launch_bounds__(256)
void k_cscatter(const int* __restrict__ rows, const int* __restrict__ cols,
                const float* __restrict__ vals, int* __restrict__ ccur,
                uint2* __restrict__ sedge, int E, int nb, int chunk) {
    __shared__ int lcnt[NBMAX];
    __shared__ int lbase[NBMAX];
    int t = threadIdx.x;
    int c0 = blockIdx.x * chunk;
    int c1 = min(c0 + chunk, E);
    for (int i = t; i < nb; i += 256) lcnt[i] = 0;
    __syncthreads();
    for (int e = c0 + t; e < c1; e += 256)
        atomicAdd(&lcnt[rows[e] >> 7], 1);
    __syncthreads();
    for (int i = t; i < nb; i += 256) {
        int c = lcnt[i];
        lbase[i] = c ? atomicAdd(&ccur[i], c) : 0;
        lcnt[i] = 0;
    }
    __syncthreads();
    for (int e = c0 + t; e < c1; e += 256) {
        int r = rows[e];
        int b = r >> 7;
        int rk = atomicAdd(&lcnt[b], 1);
        uint2 ed;
        ed.x = (unsigned)cols[e] | ((unsigned)(r & (BR - 1)) << 16);
        ed.y = __float_as_uint(vals[e]);
        sedge[lbase[b] + rk] = ed;
    }
}

// ---- per-bucket fine CSR sort in LDS ----
__global__ __launch_bounds__(256)
void k_fine(const uint2* __restrict__ sedge, const int* __restrict__ cbase,
            uint2* __restrict__ sedge2, int* __restrict__ noff, int N, int nb) {
    __shared__ int cnt[BR], sbase[BR], cur[BR];
    __shared__ uint2 ebuf[FCAP];
    int b = blockIdx.x, t = threadIdx.x;
    int e0 = cbase[b], e1 = cbase[b + 1];
    int cntE = e1 - e0;
    if (t < BR) { cnt[t] = 0; cur[t] = 0; }
    __syncthreads();
    for (int e = e0 + t; e < e1; e += 256)
        atomicAdd(&cnt[sedge[e].x >> 16], 1);
    __syncthreads();
    if (t < BR) sbase[t] = cnt[t];
    __syncthreads();
    for (int d = 1; d < BR; d <<= 1) {
        int add = (t < BR && t >= d) ? sbase[t - d] : 0;
        __syncthreads();
        if (t < BR) sbase[t] += add;
        __syncthreads();
    }
    int row0 = b * BR;
    if (t < BR) {
        int ex = sbase[t] - cnt[t];
        sbase[t] = ex;
        if (row0 + t < N) noff[row0 + t] = e0 + ex;
    }
    if (b == nb - 1 && t == 0) noff[N] = e1;
    __syncthreads();
    if (cntE <= FCAP) {
        for (int e = e0 + t; e < e1; e += 256) {
            uint2 ed = sedge[e];
            int r = ed.x >> 16;
            int p = sbase[r] + atomicAdd(&cur[r], 1);
            ebuf[p] = make_uint2(ed.x & 0xFFFFu, ed.y);
        }
        __syncthreads();
        for (int i = t; i < cntE; i += 256)
            sedge2[e0 + i] = ebuf[i];
    } else {
        for (int e = e0 + t; e < e1; e += 256) {
            uint2 ed = sedge[e];
            int r = ed.x >> 16;
            int p = e0 + sbase[r] + atomicAdd(&cur[r], 1);
            sedge2[p] = make_uint2(ed.x & 0xFFFFu, ed.y);
        }
    }
}

// ---- segment-sum gather (bf16 rows, fp32 accumulate, x8 unroll) ----
__global__ __launch_bounds__(256)
void k_gather(const unsigned* __restrict__ xh, const float* __restrict__ eps,
              const int* __restrict__ off, const uint2* __restrict__ sedge,
              unsigned* __restrict__ aggh, int N) {
    int node = blockIdx.x * 4 + (threadIdx.x >> 6);
    int lane = threadIdx.x & 63;
    if (node >= N) return;
    float s = 1.0f + eps[0];
    unsigned u = xh[(size_t)node * DH + lane];
    float ax = s * bflo(u), ay = s * bfhi(u);
    int b = off[node], e = off[node + 1];
    int i = b;
    for (; i + 8 <= e; i += 8) {
        uint2 ed[8];
        unsigned uu[8];
#pragma unroll
        for (int j = 0; j < 8; ++j) ed[j] = sedge[i + j];
#pragma unroll
        for (int j = 0; j < 8; ++j) uu[j] = xh[(size_t)ed[j].x * DH + lane];
#pragma unroll
        for (int j = 0; j < 8; ++j) {
            float v = __uint_as_float(ed[j].y);
            ax += v * bflo(uu[j]);
            ay += v * bfhi(uu[j]);
        }
    }
    for (; i < e; ++i) {
        uint2 ed = sedge[i];
        unsigned uu = xh[(size_t)ed.x * DH + lane];
        float v = __uint_as_float(ed.y);
        ax += v * bflo(uu);
        ay += v * bfhi(uu);
    }
    aggh[(size_t)node * DH + lane] = (unsigned)f2bf(ax) | ((unsigned)f2bf(ay) << 16);
}

// ---- layer-1 MFMA GEMM + fused batch-stat partials ----
__global__ __launch_bounds__(256)
void k_gemm(const unsigned short* __restrict__ A, const unsigned short* __restrict__ Wsw,
            const float* __restrict__ bias, unsigned short* __restrict__ Hout,
            float* __restrict__ stats, int N) {
    __shared__ float redS[4 * D];
    __shared__ float redQ[4 * D];
    int tid = threadIdx.x, lane = tid & 63, w = tid >> 6;
    int row0 = blockIdx.x * 64 + w * 16;
    int m = lane & 15, quad = lane >> 4;

    f32x4 acc[8];
#pragma unroll
    for (int nt = 0; nt < 8; ++nt) acc[nt] = (f32x4){0.f, 0.f, 0.f, 0.f};

    int arow = row0 + m;
    bool avalid = arow < N;
    const s16x8* wp = (const s16x8*)Wsw;
    s16x8 az = {0, 0, 0, 0, 0, 0, 0, 0};
#pragma unroll
    for (int kt = 0; kt < 4; ++kt) {
        s16x8 a = avalid ? *(const s16x8*)&A[(size_t)arow * D + kt * 32 + quad * 8] : az;
#pragma unroll
        for (int nt = 0; nt < 8; ++nt) {
            s16x8 b = wp[(kt * 8 + nt) * 64 + lane];
            acc[nt] = __builtin_amdgcn_mfma_f32_16x16x32_bf16(a, b, acc[nt], 0, 0, 0);
        }
    }

#pragma unroll
    for (int nt = 0; nt < 8; ++nt) {
        float bv = bias[nt * 16 + m];
        float s = 0.f, q = 0.f;
#pragma unroll
        for (int r = 0; r < 4; ++r) {
            int row = row0 + quad * 4 + r;
            float h = acc[nt][r] + bv;
            if (row < N) {
                Hout[(size_t)row * D + nt * 16 + m] = f2bf(h);
                s += h; q += h * h;
            }
        }
        s += __shfl_xor(s, 16, 64); s += __shfl_xor(s, 32, 64);
        q += __shfl_xor(q, 16, 64); q += __shfl_xor(q, 32, 64);
        if (quad == 0) {
            redS[w * D + nt * 16 + m] = s;
            redQ[w * D + nt * 16 + m] = q;
        }
    }
    __syncthreads();
    if (tid < D) {
        float ts = redS[tid] + redS[D + tid] + redS[2 * D + tid] + redS[3 * D + tid];
        float tq = redQ[tid] + redQ[D + tid] + redQ[2 * D + tid] + redQ[3 * D + tid];
        atomicAdd(&stats[tid], ts);
        atomicAdd(&stats[D + tid], tq);
    }
}

// ---- layer-2 GEMM with BN1+swish fused into the A-load; stats2 partials ----
__global__ __launch_bounds__(256)
void k_gemm2f(const unsigned short* __restrict__ H1, const unsigned short* __restrict__ Wsw,
              const float* __restrict__ bias, const float* __restrict__ stats1,
              const float* __restrict__ g1, const float* __restrict__ be1, float invN,
              unsigned short* __restrict__ Hout, float* __restrict__ stats2, int N) {
    __shared__ float redS[4 * D];
    __shared__ float redQ[4 * D];
    __shared__ float sa[D], sb[D];
    int tid = threadIdx.x, lane = tid & 63, w = tid >> 6;
    if (tid < D) {
        float mean = stats1[tid] * invN;
        float var = fmaxf(stats1[D + tid] * invN - mean * mean, 0.f);
        float a = g1[tid] * rsqrtf(var + 1e-5f);
        sa[tid] = a;
        sb[tid] = be1[tid] - mean * a;
    }
    __syncthreads();

    int row0 = blockIdx.x * 64 + w * 16;
    int m = lane & 15, quad = lane >> 4;

    f32x4 acc[8];
#pragma unroll
    for (int nt = 0; nt < 8; ++nt) acc[nt] = (f32x4){0.f, 0.f, 0.f, 0.f};

    int arow = row0 + m;
    bool avalid = arow < N;
    const s16x8* wp = (const s16x8*)Wsw;
    s16x8 az = {0, 0, 0, 0, 0, 0, 0, 0};
#pragma unroll
    for (int kt = 0; kt < 4; ++kt) {
        s16x8 a = az;
        if (avalid) {
            s16x8 raw = *(const s16x8*)&H1[(size_t)arow * D + kt * 32 + quad * 8];
#pragma unroll
            for (int j = 0; j < 8; ++j) {
                int k = kt * 32 + quad * 8 + j;
                float dd = bf2f(raw[j]) * sa[k] + sb[k];
                float o = dd / (1.f + __expf(-dd));
                a[j] = (short)f2bf(o);
            }
        }
#pragma unroll
        for (int nt = 0; nt < 8; ++nt) {
            s16x8 b = wp[(kt * 8 + nt) * 64 + lane];
            acc[nt] = __builtin_amdgcn_mfma_f32_16x16x32_bf16(a, b, acc[nt], 0, 0, 0);
        }
    }

#pragma unroll
    for (int nt = 0; nt < 8; ++nt) {
        float bv = bias[nt * 16 + m];
        float s = 0.f, q = 0.f;
#pragma unroll
        for (int r = 0; r < 4; ++r) {
            int row = row0 + quad * 4 + r;
            float h = acc[nt][r] + bv;
            if (row < N) {
                Hout[(size_t)row * D + nt * 16 + m] = f2bf(h);
                s += h; q += h * h;
            }
        }
        s += __shfl_xor(s, 16, 64); s += __shfl_xor(s, 32, 64);
        q += __shfl_xor(q, 16, 64); q += __shfl_xor(q, 32, 64);
        if (quad == 0) {
            redS[w * D + nt * 16 + m] = s;
            redQ[w * D + nt * 16 + m] = q;
        }
    }
    __syncthreads();
    if (tid < D) {
        float ts = redS[tid] + redS[D + tid] + redS[2 * D + tid] + redS[3 * D + tid];
        float tq = redQ[tid] + redQ[D + tid] + redQ[2 * D + tid] + redQ[3 * D + tid];
        atomicAdd(&stats2[tid], ts);
        atomicAdd(&stats2[D + tid], tq);
    }
}

// ---- final BN + swish -> fp32 out (finalize fused from raw sums) ----
__global__ void k_bnswish(const unsigned* __restrict__ inh, float* __restrict__ outp,
                          const float* __restrict__ stats, const float* __restrict__ g,
                          const float* __restrict__ be, float invN, int total4) {
    __shared__ float sa[D], sb[D];
    int j = threadIdx.x;
    if (j < D) {
        float mean = stats[j] * invN;
        float var = fmaxf(stats[D + j] * invN - mean * mean, 0.f);
        float a = g[j] * rsqrtf(var + 1e-5f);
        sa[j] = a;
        sb[j] = be[j] - mean * a;
    }
    __syncthreads();
    int i = blockIdx.x * blockDim.x + threadIdx.x;
    if (i >= total4) return;
    uint2 u = ((const uint2*)inh)[i];
    int c = (i * 4) & (D - 1);
    float d0 = bflo(u.x) * sa[c + 0] + sb[c + 0];
    float d1 = bfhi(u.x) * sa[c + 1] + sb[c + 1];
    float d2 = bflo(u.y) * sa[c + 2] + sb[c + 2];
    float d3 = bfhi(u.y) * sa[c + 3] + sb[c + 3];
    float o0 = d0 / (1.f + __expf(-d0));
    float o1 = d1 / (1.f + __expf(-d1));
    float o2 = d2 / (1.f + __expf(-d2));
    float o3 = d3 / (1.f + __expf(-d3));
    ((float4*)outp)[i] = make_float4(o0, o1, o2, o3);
}

extern "C" void kernel_launch(void* const* d_in, const int* in_sizes, int n_in,
                              void* d_out, int out_size, void* d_ws, size_t ws_size,
                              hipStream_t stream) {
    const float* x    = (const float*)d_in[0];
    const float* vals = (const float*)d_in[1];
    const float* W1   = (const float*)d_in[2];
    const float* b1   = (const float*)d_in[3];
    const float* g1   = (const float*)d_in[4];
    const float* be1  = (const float*)d_in[5];
    const float* W2   = (const float*)d_in[6];
    const float* b2   = (const float*)d_in[7];
    const float* g2   = (const float*)d_in[8];
    const float* be2  = (const float*)d_in[9];
    const float* eps  = (const float*)d_in[10];
    const int*  rows  = (const int*)d_in[11];
    const int*  cols  = (const int*)d_in[12];
    float* out = (float*)d_out;

    int N = in_sizes[0] / D;
    int E = in_sizes[1];
    int nb = (N + BR - 1) / BR;

    // ---- workspace layout ----
    char* p = (char*)d_ws;
    float* stats = (float*)p;              p += 4 * D * sizeof(float);   // stats1 | stats2
    int* gpart = (int*)p;                  p += (size_t)HB * NBMAX * sizeof(int);
    int* cbase = (int*)p;                  p += (size_t)(NBMAX + 1) * sizeof(int);
    int* ccur = (int*)p;                   p += (size_t)NBMAX * sizeof(int);
    int* noff = (int*)p;                   p += (size_t)(N + 2) * sizeof(int);
    p = (char*)(((uintptr_t)p + 15) & ~(uintptr_t)15);
    unsigned short* Wsw1 = (unsigned short*)p; p += (size_t)D * D * 2;
    unsigned short* Wsw2 = (unsigned short*)p; p += (size_t)D * D * 2;
    p = (char*)(((uintptr_t)p + 15) & ~(uintptr_t)15);
    uint2* sedge  = (uint2*)p;             p += (size_t)E * sizeof(uint2);
    uint2* sedge2 = (uint2*)p;             p += (size_t)E * sizeof(uint2);
    unsigned* xh = (unsigned*)p;           p += (size_t)N * DH * sizeof(unsigned);  // also H1
    unsigned* aggh = (unsigned*)p;         /* N*DH uints; also H2 */

    float* stats1 = stats;
    float* stats2 = stats + 2 * D;

    int total4 = N * D / 4;
    int eb = (total4 + 255) / 256;
    int gblk = (N + 63) / 64;
    int chunk = (E + 255) / 256;
    float invN = 1.0f / (float)N;

    // 1. fused setup: xpack | hist partials | prepw
    k_setup<<<eb + HB + 16, 256, 0, stream>>>(x, xh, total4, rows, gpart, E,
                                              W1, W2, Wsw1, Wsw2, eb, nb);
    // 2. reduce+scan bucket counts; zero stats
    k_cscan<<<1, 512, 0, stream>>>(gpart, cbase, ccur, stats, nb);
    // 3. coarse scatter
    k_cscatter<<<256, 256, 0, stream>>>(rows, cols, vals, ccur, sedge, E, nb, chunk);
    // 4. per-bucket fine sort
    k_fine<<<nb, 256, 0, stream>>>(sedge, cbase, sedge2, noff, N, nb);
    // 5. gather
    k_gather<<<(N + 3) / 4, 256, 0, stream>>>(xh, eps, noff, sedge2, aggh, N);
    // 6. layer-1 GEMM (+stats1); H1 -> xh
    k_gemm<<<gblk, 256, 0, stream>>>((const unsigned short*)aggh, Wsw1, b1,
                                     (unsigned short*)xh, stats1, N);
    // 7. layer-2 GEMM with BN1+swish fused on A; H2 -> aggh (+stats2)
    k_gemm2f<<<gblk, 256, 0, stream>>>((const unsigned short*)xh, Wsw2, b2,
                                       stats1, g1, be1, invN,
                                       (unsigned short*)aggh, stats2, N);
    // 8. final BN+swish -> fp32 out
    k_bnswish<<<eb, 256, 0, stream>>>(aggh, out, stats2, g2, be2, invN, total4);
}

// Round 7
// 258.776 us; speedup vs baseline: 3.6146x; 1.0355x over previous
//
#include <hip/hip_runtime.h>

#define D 128
#define DH 64      // uints per feature row (2 bf16 per uint)
#define BR 128     // rows per coarse bucket
#define NBMAX 512
#define HB 64      // histogram partial blocks
#define FCAP 4096  // max edges per bucket staged in LDS (exp ~2046 +- 45)
#define GT 1024    // threads in sortgather

typedef float f32x4 __attribute__((ext_vector_type(4)));
typedef short s16x8 __attribute__((ext_vector_type(8)));

static __device__ __forceinline__ unsigned short f2bf(float f) {
    unsigned u = __float_as_uint(f);
    u += 0x7FFF + ((u >> 16) & 1);   // RNE
    return (unsigned short)(u >> 16);
}
static __device__ __forceinline__ float bflo(unsigned u) { return __uint_as_float(u << 16); }
static __device__ __forceinline__ float bfhi(unsigned u) { return __uint_as_float(u & 0xFFFF0000u); }
static __device__ __forceinline__ float bf2f(short v) {
    return __uint_as_float(((unsigned)(unsigned short)v) << 16);
}

// ---- fused setup: [0,eb) xpack | [eb,eb+HB) row histogram partials | [eb+HB,+16) prepw ----
__global__ __launch_bounds__(256)
void k_setup(const float* __restrict__ x, unsigned* __restrict__ xh, int total4,
             const int* __restrict__ rows, int* __restrict__ gpart, int E,
             const float* __restrict__ W1, const float* __restrict__ W2,
             unsigned short* __restrict__ Wsw1, unsigned short* __restrict__ Wsw2,
             int eb, int nb) {
    __shared__ int h[NBMAX];
    int bid = blockIdx.x, t = threadIdx.x;
    if (bid < eb) {
        int i = bid * 256 + t;
        if (i < total4) {
            float4 v = ((const float4*)x)[i];
            uint2 o;
            o.x = (unsigned)f2bf(v.x) | ((unsigned)f2bf(v.y) << 16);
            o.y = (unsigned)f2bf(v.z) | ((unsigned)f2bf(v.w) << 16);
            ((uint2*)xh)[i] = o;
        }
    } else if (bid < eb + HB) {
        int hb = bid - eb;
        for (int i = t; i < nb; i += 256) h[i] = 0;
        __syncthreads();
        int chunk = (E + HB - 1) / HB;
        int e0 = hb * chunk, e1 = min(e0 + chunk, E);
        for (int e = e0 + t; e < e1; e += 256)
            atomicAdd(&h[rows[e] >> 7], 1);
        __syncthreads();
        for (int i = t; i < nb; i += 256) gpart[hb * NBMAX + i] = h[i];
    } else {
        int gidx = (bid - eb - HB) * 256 + t;   // 0..4095
        const float* W = (gidx < 2048) ? W1 : W2;
        unsigned short* Wsw = (gidx < 2048) ? Wsw1 : Wsw2;
        int idx = gidx & 2047;
        int lane = idx & 63, nt = (idx >> 6) & 7, kt = idx >> 9;
        int k0 = kt * 32 + (lane >> 4) * 8;
        int n = nt * 16 + (lane & 15);
        unsigned short* dst = &Wsw[(size_t)((kt * 8 + nt) * 64 + lane) * 8];
#pragma unroll
        for (int j = 0; j < 8; ++j) dst[j] = f2bf(W[(k0 + j) * D + n]);
    }
}

// ---- reduce histogram partials, scan -> cbase/ccur; zero stats (512 floats) ----
__global__ __launch_bounds__(512)
void k_cscan(const int* __restrict__ gpart, int* __restrict__ cbase,
             int* __restrict__ ccur, float* __restrict__ stats, int nb) {
    __shared__ int s[512];
    int t = threadIdx.x;
    int v = 0;
    if (t < nb)
        for (int hb = 0; hb < HB; ++hb) v += gpart[hb * NBMAX + t];
    s[t] = v;
    __syncthreads();
    for (int d = 1; d < 512; d <<= 1) {
        int add = (t >= d) ? s[t - d] : 0;
        __syncthreads();
        s[t] += add;
        __syncthreads();
    }
    if (t < nb) {
        int excl = s[t] - v;
        cbase[t] = excl;
        ccur[t] = excl;
    }
    if (t == nb - 1) cbase[nb] = s[t];
    stats[t] = 0.f;   // 4*D = 512 floats: stats1 | stats2
}

// ---- coarse scatter: edges -> bucket-grouped sedge, LDS-staged for write locality ----
__global__ __launch_bounds__(256)
void k_cscatter(const int* __restrict__ rows, const int* __restrict__ cols,
                const float* __restrict__ vals, int* __restrict__ ccur,
                uint2* __restrict__ sedge, int E, int nb, int chunk) {
    __shared__ int lcnt[NBMAX];
    __shared__ int lbase[NBMAX];
    int t = threadIdx.x;
    int c0 = blockIdx.x * chunk;
    int c1 = min(c0 + chunk, E);
    for (int i = t; i < nb; i += 256) lcnt[i] = 0;
    __syncthreads();
    for (int e = c0 + t; e < c1; e += 256)
        atomicAdd(&lcnt[rows[e] >> 7], 1);
    __syncthreads();
    for (int i = t; i < nb; i += 256) {
        int c = lcnt[i];
        lbase[i] = c ? atomicAdd(&ccur[i], c) : 0;
        lcnt[i] = 0;
    }
    __syncthreads();
    for (int e = c0 + t; e < c1; e += 256) {
        int r = rows[e];
        int b = r >> 7;
        int rk = atomicAdd(&lcnt[b], 1);
        uint2 ed;
        ed.x = (unsigned)cols[e] | ((unsigned)(r & (BR - 1)) << 16);
        ed.y = __float_as_uint(vals[e]);
        sedge[lbase[b] + rk] = ed;
    }
}

// ---- fused per-bucket fine sort (LDS) + segment-sum gather ----
// Phase 1: stage bucket edges in LDS + row counts. Phase 2: LDS scan.
// Phase 3: place into row-sorted LDS buffer. Phase 4: wave w gathers rows w,w+16,...
__global__ __launch_bounds__(GT, 2)
void k_sortgather(const uint2* __restrict__ sedge, const int* __restrict__ cbase,
                  const unsigned* __restrict__ xh, const float* __restrict__ eps,
                  unsigned* __restrict__ aggh, int N) {
    __shared__ int cnt[BR], sbase[BR], cur[BR];
    __shared__ uint2 ebufA[FCAP];   // raw staged edges
    __shared__ uint2 ebufB[FCAP];   // row-sorted edges
    int b = blockIdx.x, t = threadIdx.x;
    int e0 = cbase[b], e1 = cbase[b + 1];
    int cntE = e1 - e0;
    bool fits = (cntE <= FCAP);
    if (t < BR) { cnt[t] = 0; cur[t] = 0; }
    __syncthreads();
    if (fits) {
        for (int i = t; i < cntE; i += GT) {
            uint2 ed = sedge[e0 + i];
            ebufA[i] = ed;
            atomicAdd(&cnt[ed.x >> 16], 1);
        }
    } else {
        for (int i = t; i < cntE; i += GT)
            atomicAdd(&cnt[sedge[e0 + i].x >> 16], 1);
    }
    __syncthreads();
    if (t < BR) sbase[t] = cnt[t];
    __syncthreads();
    for (int d = 1; d < BR; d <<= 1) {
        int add = (t < BR && t >= d) ? sbase[t - d] : 0;
        __syncthreads();
        if (t < BR) sbase[t] += add;
        __syncthreads();
    }
    if (t < BR) sbase[t] -= cnt[t];   // exclusive prefix
    __syncthreads();
    if (fits) {
        for (int i = t; i < cntE; i += GT) {
            uint2 ed = ebufA[i];
            int r = ed.x >> 16;
            int p = sbase[r] + atomicAdd(&cur[r], 1);
            ebufB[p] = make_uint2(ed.x & 0xFFFFu, ed.y);
        }
        __syncthreads();
    }

    // ---- gather phase: 16 waves, wave w owns rows w, w+16, ... ----
    int lane = t & 63, w = t >> 6;
    float s = 1.0f + eps[0];
    int row0 = b * BR;
    for (int rl = w; rl < BR; rl += 16) {
        int grow = row0 + rl;
        if (grow >= N) break;
        unsigned u = xh[(size_t)grow * DH + lane];
        float ax = s * bflo(u), ay = s * bfhi(u);
        if (fits) {
            int i = sbase[rl];
            int i1 = (rl < BR - 1) ? sbase[rl + 1] : cntE;
            for (; i + 8 <= i1; i += 8) {
                uint2 ed[8];
                unsigned uu[8];
#pragma unroll
                for (int j = 0; j < 8; ++j) ed[j] = ebufB[i + j];
#pragma unroll
                for (int j = 0; j < 8; ++j) uu[j] = xh[(size_t)ed[j].x * DH + lane];
#pragma unroll
                for (int j = 0; j < 8; ++j) {
                    float v = __uint_as_float(ed[j].y);
                    ax += v * bflo(uu[j]);
                    ay += v * bfhi(uu[j]);
                }
            }
            for (; i < i1; ++i) {
                uint2 ed = ebufB[i];
                unsigned uu = xh[(size_t)ed.x * DH + lane];
                float v = __uint_as_float(ed.y);
                ax += v * bflo(uu);
                ay += v * bfhi(uu);
            }
        } else {  // fallback: O(cntE) scan from global (statistically never)
            for (int i = 0; i < cntE; ++i) {
                uint2 ed = sedge[e0 + i];
                if ((int)(ed.x >> 16) == rl) {
                    unsigned uu = xh[(size_t)(ed.x & 0xFFFFu) * DH + lane];
                    float v = __uint_as_float(ed.y);
                    ax += v * bflo(uu);
                    ay += v * bfhi(uu);
                }
            }
        }
        aggh[(size_t)grow * DH + lane] = (unsigned)f2bf(ax) | ((unsigned)f2bf(ay) << 16);
    }
}

// ---- layer-1 MFMA GEMM + fused batch-stat partials ----
__global__ __launch_bounds__(256)
void k_gemm(const unsigned short* __restrict__ A, const unsigned short* __restrict__ Wsw,
            const float* __restrict__ bias, unsigned short* __restrict__ Hout,
            float* __restrict__ stats, int N) {
    __shared__ float redS[4 * D];
    __shared__ float redQ[4 * D];
    int tid = threadIdx.x, lane = tid & 63, w = tid >> 6;
    int row0 = blockIdx.x * 64 + w * 16;
    int m = lane & 15, quad = lane >> 4;

    f32x4 acc[8];
#pragma unroll
    for (int nt = 0; nt < 8; ++nt) acc[nt] = (f32x4){0.f, 0.f, 0.f, 0.f};

    int arow = row0 + m;
    bool avalid = arow < N;
    const s16x8* wp = (const s16x8*)Wsw;
    s16x8 az = {0, 0, 0, 0, 0, 0, 0, 0};
#pragma unroll
    for (int kt = 0; kt < 4; ++kt) {
        s16x8 a = avalid ? *(const s16x8*)&A[(size_t)arow * D + kt * 32 + quad * 8] : az;
#pragma unroll
        for (int nt = 0; nt < 8; ++nt) {
            s16x8 b = wp[(kt * 8 + nt) * 64 + lane];
            acc[nt] = __builtin_amdgcn_mfma_f32_16x16x32_bf16(a, b, acc[nt], 0, 0, 0);
        }
    }

#pragma unroll
    for (int nt = 0; nt < 8; ++nt) {
        float bv = bias[nt * 16 + m];
        float s = 0.f, q = 0.f;
#pragma unroll
        for (int r = 0; r < 4; ++r) {
            int row = row0 + quad * 4 + r;
            float h = acc[nt][r] + bv;
            if (row < N) {
                Hout[(size_t)row * D + nt * 16 + m] = f2bf(h);
                s += h; q += h * h;
            }
        }
        s += __shfl_xor(s, 16, 64); s += __shfl_xor(s, 32, 64);
        q += __shfl_xor(q, 16, 64); q += __shfl_xor(q, 32, 64);
        if (quad == 0) {
            redS[w * D + nt * 16 + m] = s;
            redQ[w * D + nt * 16 + m] = q;
        }
    }
    __syncthreads();
    if (tid < D) {
        float ts = redS[tid] + redS[D + tid] + redS[2 * D + tid] + redS[3 * D + tid];
        float tq = redQ[tid] + redQ[D + tid] + redQ[2 * D + tid] + redQ[3 * D + tid];
        atomicAdd(&stats[tid], ts);
        atomicAdd(&stats[D + tid], tq);
    }
}

// ---- layer-2 GEMM with BN1+swish fused into the A-load; stats2 partials ----
__global__ __launch_bounds__(256)
void k_gemm2f(const unsigned short* __restrict__ H1, const unsigned short* __restrict__ Wsw,
              const float* __restrict__ bias, const float* __restrict__ stats1,
              const float* __restrict__ g1, const float* __restrict__ be1, float invN,
              unsigned short* __restrict__ Hout, float* __restrict__ stats2, int N) {
    __shared__ float redS[4 * D];
    __shared__ float redQ[4 * D];
    __shared__ float sa[D], sb[D];
    int tid = threadIdx.x, lane = tid & 63, w = tid >> 6;
    if (tid < D) {
        float mean = stats1[tid] * invN;
        float var = fmaxf(stats1[D + tid] * invN - mean * mean, 0.f);
        float a = g1[tid] * rsqrtf(var + 1e-5f);
        sa[tid] = a;
        sb[tid] = be1[tid] - mean * a;
    }
    __syncthreads();

    int row0 = blockIdx.x * 64 + w * 16;
    int m = lane & 15, quad = lane >> 4;

    f32x4 acc[8];
#pragma unroll
    for (int nt = 0; nt < 8; ++nt) acc[nt] = (f32x4){0.f, 0.f, 0.f, 0.f};

    int arow = row0 + m;
    bool avalid = arow < N;
    const s16x8* wp = (const s16x8*)Wsw;
    s16x8 az = {0, 0, 0, 0, 0, 0, 0, 0};
#pragma unroll
    for (int kt = 0; kt < 4; ++kt) {
        s16x8 a = az;
        if (avalid) {
            s16x8 raw = *(const s16x8*)&H1[(size_t)arow * D + kt * 32 + quad * 8];
#pragma unroll
            for (int j = 0; j < 8; ++j) {
                int k = kt * 32 + quad * 8 + j;
                float dd = bf2f(raw[j]) * sa[k] + sb[k];
                float o = dd / (1.f + __expf(-dd));
                a[j] = (short)f2bf(o);
            }
        }
#pragma unroll
        for (int nt = 0; nt < 8; ++nt) {
            s16x8 b = wp[(kt * 8 + nt) * 64 + lane];
            acc[nt] = __builtin_amdgcn_mfma_f32_16x16x32_bf16(a, b, acc[nt], 0, 0, 0);
        }
    }

#pragma unroll
    for (int nt = 0; nt < 8; ++nt) {
        float bv = bias[nt * 16 + m];
        float s = 0.f, q = 0.f;
#pragma unroll
        for (int r = 0; r < 4; ++r) {
            int row = row0 + quad * 4 + r;
            float h = acc[nt][r] + bv;
            if (row < N) {
                Hout[(size_t)row * D + nt * 16 + m] = f2bf(h);
                s += h; q += h * h;
            }
        }
        s += __shfl_xor(s, 16, 64); s += __shfl_xor(s, 32, 64);
        q += __shfl_xor(q, 16, 64); q += __shfl_xor(q, 32, 64);
        if (quad == 0) {
            redS[w * D + nt * 16 + m] = s;
            redQ[w * D + nt * 16 + m] = q;
        }
    }
    __syncthreads();
    if (tid < D) {
        float ts = redS[tid] + redS[D + tid] + redS[2 * D + tid] + redS[3 * D + tid];
        float tq = redQ[tid] + redQ[D + tid] + redQ[2 * D + tid] + redQ[3 * D + tid];
        atomicAdd(&stats2[tid], ts);
        atomicAdd(&stats2[D + tid], tq);
    }
}

// ---- final BN + swish -> fp32 out (finalize fused from raw sums) ----
__global__ void k_bnswish(const unsigned* __restrict__ inh, float* __restrict__ outp,
                          const float* __restrict__ stats, const float* __restrict__ g,
                          const float* __restrict__ be, float invN, int total4) {
    __shared__ float sa[D], sb[D];
    int j = threadIdx.x;
    if (j < D) {
        float mean = stats[j] * invN;
        float var = fmaxf(stats[D + j] * invN - mean * mean, 0.f);
        float a = g[j] * rsqrtf(var + 1e-5f);
        sa[j] = a;
        sb[j] = be[j] - mean * a;
    }
    __syncthreads();
    int i = blockIdx.x * blockDim.x + threadIdx.x;
    if (i >= total4) return;
    uint2 u = ((const uint2*)inh)[i];
    int c = (i * 4) & (D - 1);
    float d0 = bflo(u.x) * sa[c + 0] + sb[c + 0];
    float d1 = bfhi(u.x) * sa[c + 1] + sb[c + 1];
    float d2 = bflo(u.y) * sa[c + 2] + sb[c + 2];
    float d3 = bfhi(u.y) * sa[c + 3] + sb[c + 3];
    float o0 = d0 / (1.f + __expf(-d0));
    float o1 = d1 / (1.f + __expf(-d1));
    float o2 = d2 / (1.f + __expf(-d2));
    float o3 = d3 / (1.f + __expf(-d3));
    ((float4*)outp)[i] = make_float4(o0, o1, o2, o3);
}

extern "C" void kernel_launch(void* const* d_in, const int* in_sizes, int n_in,
                              void* d_out, int out_size, void* d_ws, size_t ws_size,
                              hipStream_t stream) {
    const float* x    = (const float*)d_in[0];
    const float* vals = (const float*)d_in[1];
    const float* W1   = (const float*)d_in[2];
    const float* b1   = (const float*)d_in[3];
    const float* g1   = (const float*)d_in[4];
    const float* be1  = (const float*)d_in[5];
    const float* W2   = (const float*)d_in[6];
    const float* b2   = (const float*)d_in[7];
    const float* g2   = (const float*)d_in[8];
    const float* be2  = (const float*)d_in[9];
    const float* eps  = (const float*)d_in[10];
    const int*  rows  = (const int*)d_in[11];
    const int*  cols  = (const int*)d_in[12];
    float* out = (float*)d_out;

    int N = in_sizes[0] / D;
    int E = in_sizes[1];
    int nb = (N + BR - 1) / BR;

    // ---- workspace layout ----
    char* p = (char*)d_ws;
    float* stats = (float*)p;              p += 4 * D * sizeof(float);   // stats1 | stats2
    int* gpart = (int*)p;                  p += (size_t)HB * NBMAX * sizeof(int);
    int* cbase = (int*)p;                  p += (size_t)(NBMAX + 1) * sizeof(int);
    int* ccur = (int*)p;                   p += (size_t)NBMAX * sizeof(int);
    p = (char*)(((uintptr_t)p + 15) & ~(uintptr_t)15);
    unsigned short* Wsw1 = (unsigned short*)p; p += (size_t)D * D * 2;
    unsigned short* Wsw2 = (unsigned short*)p; p += (size_t)D * D * 2;
    p = (char*)(((uintptr_t)p + 15) & ~(uintptr_t)15);
    uint2* sedge  = (uint2*)p;             p += (size_t)E * sizeof(uint2);
    unsigned* xh = (unsigned*)p;           p += (size_t)N * DH * sizeof(unsigned);  // also H1
    unsigned* aggh = (unsigned*)p;         /* N*DH uints; also H2 */

    float* stats1 = stats;
    float* stats2 = stats + 2 * D;

    int total4 = N * D / 4;
    int eb = (total4 + 255) / 256;
    int gblk = (N + 63) / 64;
    int chunk = (E + 255) / 256;
    float invN = 1.0f / (float)N;

    // 1. fused setup: xpack | hist partials | prepw
    k_setup<<<eb + HB + 16, 256, 0, stream>>>(x, xh, total4, rows, gpart, E,
                                              W1, W2, Wsw1, Wsw2, eb, nb);
    // 2. reduce+scan bucket counts; zero stats
    k_cscan<<<1, 512, 0, stream>>>(gpart, cbase, ccur, stats, nb);
    // 3. coarse scatter
    k_cscatter<<<256, 256, 0, stream>>>(rows, cols, vals, ccur, sedge, E, nb, chunk);
    // 4. fused fine sort + gather
    k_sortgather<<<nb, GT, 0, stream>>>(sedge, cbase, xh, eps, aggh, N);
    // 5. layer-1 GEMM (+stats1); H1 -> xh
    k_gemm<<<gblk, 256, 0, stream>>>((const unsigned short*)aggh, Wsw1, b1,
                                     (unsigned short*)xh, stats1, N);
    // 6. layer-2 GEMM with BN1+swish fused on A; H2 -> aggh (+stats2)
    k_gemm2f<<<gblk, 256, 0, stream>>>((const unsigned short*)xh, Wsw2, b2,
                                       stats1, g1, be1, invN,
                                       (unsigned short*)aggh, stats2, N);
    // 7. final BN+swish -> fp32 out
    k_bnswish<<<eb, 256, 0, stream>>>(aggh, out, stats2, g2, be2, invN, total4);
}

// Round 9
// 254.464 us; speedup vs baseline: 3.6759x; 1.0169x over previous
//
#include <hip/hip_runtime.h>

#define D 128
#define DH 64      // uints per feature row (2 bf16 per uint)
#define BR 64      // rows per coarse bucket (64 -> 782 buckets, balanced at 4 blk/CU)
#define BSH 6      // log2(BR)
#define NBMAX 1024
#define HB 64      // histogram partial blocks
#define FCAP 2048  // max edges per bucket staged in LDS (exp ~1024 +- 32)
#define GT 512     // threads in sortgather (8 waves)

typedef float f32x4 __attribute__((ext_vector_type(4)));
typedef short s16x8 __attribute__((ext_vector_type(8)));

static __device__ __forceinline__ unsigned short f2bf(float f) {
    unsigned u = __float_as_uint(f);
    u += 0x7FFF + ((u >> 16) & 1);   // RNE
    return (unsigned short)(u >> 16);
}
static __device__ __forceinline__ float bflo(unsigned u) { return __uint_as_float(u << 16); }
static __device__ __forceinline__ float bfhi(unsigned u) { return __uint_as_float(u & 0xFFFF0000u); }
static __device__ __forceinline__ float bf2f(short v) {
    return __uint_as_float(((unsigned)(unsigned short)v) << 16);
}

// ---- fused setup: [0,eb) xpack | [eb,eb+HB) row histogram partials | [eb+HB,+16) prepw ----
__global__ __launch_bounds__(256)
void k_setup(const float* __restrict__ x, unsigned* __restrict__ xh, int total4,
             const int* __restrict__ rows, int* __restrict__ gpart, int E,
             const float* __restrict__ W1, const float* __restrict__ W2,
             unsigned short* __restrict__ Wsw1, unsigned short* __restrict__ Wsw2,
             int eb, int nb) {
    __shared__ int h[NBMAX];
    int bid = blockIdx.x, t = threadIdx.x;
    if (bid < eb) {
        int i = bid * 256 + t;
        if (i < total4) {
            float4 v = ((const float4*)x)[i];
            uint2 o;
            o.x = (unsigned)f2bf(v.x) | ((unsigned)f2bf(v.y) << 16);
            o.y = (unsigned)f2bf(v.z) | ((unsigned)f2bf(v.w) << 16);
            ((uint2*)xh)[i] = o;
        }
    } else if (bid < eb + HB) {
        int hb = bid - eb;
        for (int i = t; i < nb; i += 256) h[i] = 0;
        __syncthreads();
        int chunk = (E + HB - 1) / HB;
        int e0 = hb * chunk, e1 = min(e0 + chunk, E);
        for (int e = e0 + t; e < e1; e += 256)
            atomicAdd(&h[rows[e] >> BSH], 1);
        __syncthreads();
        for (int i = t; i < nb; i += 256) gpart[hb * NBMAX + i] = h[i];
    } else {
        int gidx = (bid - eb - HB) * 256 + t;   // 0..4095
        const float* W = (gidx < 2048) ? W1 : W2;
        unsigned short* Wsw = (gidx < 2048) ? Wsw1 : Wsw2;
        int idx = gidx & 2047;
        int lane = idx & 63, nt = (idx >> 6) & 7, kt = idx >> 9;
        int k0 = kt * 32 + (lane >> 4) * 8;
        int n = nt * 16 + (lane & 15);
        unsigned short* dst = &Wsw[(size_t)((kt * 8 + nt) * 64 + lane) * 8];
#pragma unroll
        for (int j = 0; j < 8; ++j) dst[j] = f2bf(W[(k0 + j) * D + n]);
    }
}

// ---- reduce histogram partials, scan (1024 wide) -> cbase/ccur; zero stats ----
__global__ __launch_bounds__(1024)
void k_cscan(const int* __restrict__ gpart, int* __restrict__ cbase,
             int* __restrict__ ccur, float* __restrict__ stats, int nb) {
    __shared__ int s[NBMAX];
    int t = threadIdx.x;
    int v = 0;
    if (t < nb)
        for (int hb = 0; hb < HB; ++hb) v += gpart[hb * NBMAX + t];
    s[t] = v;
    __syncthreads();
    for (int d = 1; d < NBMAX; d <<= 1) {
        int add = (t >= d) ? s[t - d] : 0;
        __syncthreads();
        s[t] += add;
        __syncthreads();
    }
    if (t < nb) {
        int excl = s[t] - v;
        cbase[t] = excl;
        ccur[t] = excl;
    }
    if (t == nb - 1) cbase[nb] = s[t];
    if (t < 512) stats[t] = 0.f;   // 4*D = 512 floats: stats1 | stats2
}

// ---- coarse scatter: edges -> bucket-grouped sedge, LDS-staged for write locality ----
__global__ __launch_bounds__(256)
void k_cscatter(const int* __restrict__ rows, const int* __restrict__ cols,
                const float* __restrict__ vals, int* __restrict__ ccur,
                uint2* __restrict__ sedge, int E, int nb, int chunk) {
    __shared__ int lcnt[NBMAX];
    __shared__ int lbase[NBMAX];
    int t = threadIdx.x;
    int c0 = blockIdx.x * chunk;
    int c1 = min(c0 + chunk, E);
    for (int i = t; i < nb; i += 256) lcnt[i] = 0;
    __syncthreads();
    for (int e = c0 + t; e < c1; e += 256)
        atomicAdd(&lcnt[rows[e] >> BSH], 1);
    __syncthreads();
    for (int i = t; i < nb; i += 256) {
        int c = lcnt[i];
        lbase[i] = c ? atomicAdd(&ccur[i], c) : 0;
        lcnt[i] = 0;
    }
    __syncthreads();
    for (int e = c0 + t; e < c1; e += 256) {
        int r = rows[e];
        int b = r >> BSH;
        int rk = atomicAdd(&lcnt[b], 1);
        uint2 ed;
        ed.x = (unsigned)cols[e] | ((unsigned)(r & (BR - 1)) << 16);
        ed.y = __float_as_uint(vals[e]);
        sedge[lbase[b] + rk] = ed;
    }
}

// ---- fused per-bucket fine sort (LDS) + segment-sum gather ----
// 512 thr = 8 waves; 64-row bucket; wave w gathers rows w, w+8, ...
__global__ __launch_bounds__(GT, 8)
void k_sortgather(const uint2* __restrict__ sedge, const int* __restrict__ cbase,
                  const unsigned* __restrict__ xh, const float* __restrict__ eps,
                  unsigned* __restrict__ aggh, int N) {
    __shared__ int cnt[BR], sbase[BR], cur[BR];
    __shared__ uint2 ebufA[FCAP];   // raw staged edges
    __shared__ uint2 ebufB[FCAP];   // row-sorted edges
    int b = blockIdx.x, t = threadIdx.x;
    int e0 = cbase[b], e1 = cbase[b + 1];
    int cntE = e1 - e0;
    bool fits = (cntE <= FCAP);
    if (t < BR) { cnt[t] = 0; cur[t] = 0; }
    __syncthreads();
    if (fits) {
        for (int i = t; i < cntE; i += GT) {
            uint2 ed = sedge[e0 + i];
            ebufA[i] = ed;
            atomicAdd(&cnt[ed.x >> 16], 1);
        }
    } else {
        for (int i = t; i < cntE; i += GT)
            atomicAdd(&cnt[sedge[e0 + i].x >> 16], 1);
    }
    __syncthreads();
    if (t < BR) sbase[t] = cnt[t];
    __syncthreads();
    for (int d = 1; d < BR; d <<= 1) {
        int add = (t < BR && t >= d) ? sbase[t - d] : 0;
        __syncthreads();
        if (t < BR) sbase[t] += add;
        __syncthreads();
    }
    if (t < BR) sbase[t] -= cnt[t];   // exclusive prefix
    __syncthreads();
    if (fits) {
        for (int i = t; i < cntE; i += GT) {
            uint2 ed = ebufA[i];
            int r = ed.x >> 16;
            int p = sbase[r] + atomicAdd(&cur[r], 1);
            ebufB[p] = make_uint2(ed.x & 0xFFFFu, ed.y);
        }
        __syncthreads();
    }

    // ---- gather phase ----
    int lane = t & 63, w = t >> 6;   // 8 waves
    float s = 1.0f + eps[0];
    int row0 = b * BR;
    for (int rl = w; rl < BR; rl += 8) {
        int grow = row0 + rl;
        if (grow >= N) break;
        unsigned u = xh[(size_t)grow * DH + lane];
        float ax = s * bflo(u), ay = s * bfhi(u);
        if (fits) {
            int i = sbase[rl];
            int i1 = (rl < BR - 1) ? sbase[rl + 1] : cntE;
            for (; i + 8 <= i1; i += 8) {
                uint2 ed[8];
                unsigned uu[8];
#pragma unroll
                for (int j = 0; j < 8; ++j) ed[j] = ebufB[i + j];
#pragma unroll
                for (int j = 0; j < 8; ++j) uu[j] = xh[(size_t)ed[j].x * DH + lane];
#pragma unroll
                for (int j = 0; j < 8; ++j) {
                    float v = __uint_as_float(ed[j].y);
                    ax += v * bflo(uu[j]);
                    ay += v * bfhi(uu[j]);
                }
            }
            for (; i < i1; ++i) {
                uint2 ed = ebufB[i];
                unsigned uu = xh[(size_t)ed.x * DH + lane];
                float v = __uint_as_float(ed.y);
                ax += v * bflo(uu);
                ay += v * bfhi(uu);
            }
        } else {  // fallback: O(cntE) scan from global (statistically never)
            for (int i = 0; i < cntE; ++i) {
                uint2 ed = sedge[e0 + i];
                if ((int)(ed.x >> 16) == rl) {
                    unsigned uu = xh[(size_t)(ed.x & 0xFFFFu) * DH + lane];
                    float v = __uint_as_float(ed.y);
                    ax += v * bflo(uu);
                    ay += v * bfhi(uu);
                }
            }
        }
        aggh[(size_t)grow * DH + lane] = (unsigned)f2bf(ax) | ((unsigned)f2bf(ay) << 16);
    }
}

// ---- layer-1 MFMA GEMM + fused batch-stat partials ----
__global__ __launch_bounds__(256)
void k_gemm(const unsigned short* __restrict__ A, const unsigned short* __restrict__ Wsw,
            const float* __restrict__ bias, unsigned short* __restrict__ Hout,
            float* __restrict__ stats, int N) {
    __shared__ float redS[4 * D];
    __shared__ float redQ[4 * D];
    int tid = threadIdx.x, lane = tid & 63, w = tid >> 6;
    int row0 = blockIdx.x * 64 + w * 16;
    int m = lane & 15, quad = lane >> 4;

    f32x4 acc[8];
#pragma unroll
    for (int nt = 0; nt < 8; ++nt) acc[nt] = (f32x4){0.f, 0.f, 0.f, 0.f};

    int arow = row0 + m;
    bool avalid = arow < N;
    const s16x8* wp = (const s16x8*)Wsw;
    s16x8 az = {0, 0, 0, 0, 0, 0, 0, 0};
#pragma unroll
    for (int kt = 0; kt < 4; ++kt) {
        s16x8 a = avalid ? *(const s16x8*)&A[(size_t)arow * D + kt * 32 + quad * 8] : az;
#pragma unroll
        for (int nt = 0; nt < 8; ++nt) {
            s16x8 b = wp[(kt * 8 + nt) * 64 + lane];
            acc[nt] = __builtin_amdgcn_mfma_f32_16x16x32_bf16(a, b, acc[nt], 0, 0, 0);
        }
    }

#pragma unroll
    for (int nt = 0; nt < 8; ++nt) {
        float bv = bias[nt * 16 + m];
        float s = 0.f, q = 0.f;
#pragma unroll
        for (int r = 0; r < 4; ++r) {
            int row = row0 + quad * 4 + r;
            float h = acc[nt][r] + bv;
            if (row < N) {
                Hout[(size_t)row * D + nt * 16 + m] = f2bf(h);
                s += h; q += h * h;
            }
        }
        s += __shfl_xor(s, 16, 64); s += __shfl_xor(s, 32, 64);
        q += __shfl_xor(q, 16, 64); q += __shfl_xor(q, 32, 64);
        if (quad == 0) {
            redS[w * D + nt * 16 + m] = s;
            redQ[w * D + nt * 16 + m] = q;
        }
    }
    __syncthreads();
    if (tid < D) {
        float ts = redS[tid] + redS[D + tid] + redS[2 * D + tid] + redS[3 * D + tid];
        float tq = redQ[tid] + redQ[D + tid] + redQ[2 * D + tid] + redQ[3 * D + tid];
        atomicAdd(&stats[tid], ts);
        atomicAdd(&stats[D + tid], tq);
    }
}

// ---- layer-2 GEMM with BN1+swish fused into the A-load; stats2 partials ----
__global__ __launch_bounds__(256)
void k_gemm2f(const unsigned short* __restrict__ H1, const unsigned short* __restrict__ Wsw,
              const float* __restrict__ bias, const float* __restrict__ stats1,
              const float* __restrict__ g1, const float* __restrict__ be1, float invN,
              unsigned short* __restrict__ Hout, float* __restrict__ stats2, int N) {
    __shared__ float redS[4 * D];
    __shared__ float redQ[4 * D];
    __shared__ float sa[D], sb[D];
    int tid = threadIdx.x, lane = tid & 63, w = tid >> 6;
    if (tid < D) {
        float mean = stats1[tid] * invN;
        float var = fmaxf(stats1[D + tid] * invN - mean * mean, 0.f);
        float a = g1[tid] * rsqrtf(var + 1e-5f);
        sa[tid] = a;
        sb[tid] = be1[tid] - mean * a;
    }
    __syncthreads();

    int row0 = blockIdx.x * 64 + w * 16;
    int m = lane & 15, quad = lane >> 4;

    f32x4 acc[8];
#pragma unroll
    for (int nt = 0; nt < 8; ++nt) acc[nt] = (f32x4){0.f, 0.f, 0.f, 0.f};

    int arow = row0 + m;
    bool avalid = arow < N;
    const s16x8* wp = (const s16x8*)Wsw;
    s16x8 az = {0, 0, 0, 0, 0, 0, 0, 0};
#pragma unroll
    for (int kt = 0; kt < 4; ++kt) {
        s16x8 a = az;
        if (avalid) {
            s16x8 raw = *(const s16x8*)&H1[(size_t)arow * D + kt * 32 + quad * 8];
#pragma unroll
            for (int j = 0; j < 8; ++j) {
                int k = kt * 32 + quad * 8 + j;
                float dd = bf2f(raw[j]) * sa[k] + sb[k];
                float o = dd / (1.f + __expf(-dd));
                a[j] = (short)f2bf(o);
            }
        }
#pragma unroll
        for (int nt = 0; nt < 8; ++nt) {
            s16x8 b = wp[(kt * 8 + nt) * 64 + lane];
            acc[nt] = __builtin_amdgcn_mfma_f32_16x16x32_bf16(a, b, acc[nt], 0, 0, 0);
        }
    }

#pragma unroll
    for (int nt = 0; nt < 8; ++nt) {
        float bv = bias[nt * 16 + m];
        float s = 0.f, q = 0.f;
#pragma unroll
        for (int r = 0; r < 4; ++r) {
            int row = row0 + quad * 4 + r;
            float h = acc[nt][r] + bv;
            if (row < N) {
                Hout[(size_t)row * D + nt * 16 + m] = f2bf(h);
                s += h; q += h * h;
            }
        }
        s += __shfl_xor(s, 16, 64); s += __shfl_xor(s, 32, 64);
        q += __shfl_xor(q, 16, 64); q += __shfl_xor(q, 32, 64);
        if (quad == 0) {
            redS[w * D + nt * 16 + m] = s;
            redQ[w * D + nt * 16 + m] = q;
        }
    }
    __syncthreads();
    if (tid < D) {
        float ts = redS[tid] + redS[D + tid] + redS[2 * D + tid] + redS[3 * D + tid];
        float tq = redQ[tid] + redQ[D + tid] + redQ[2 * D + tid] + redQ[3 * D + tid];
        atomicAdd(&stats2[tid], ts);
        atomicAdd(&stats2[D + tid], tq);
    }
}

// ---- final BN + swish -> fp32 out (finalize fused from raw sums) ----
__global__ void k_bnswish(const unsigned* __restrict__ inh, float* __restrict__ outp,
                          const float* __restrict__ stats, const float* __restrict__ g,
                          const float* __restrict__ be, float invN, int total4) {
    __shared__ float sa[D], sb[D];
    int j = threadIdx.x;
    if (j < D) {
        float mean = stats[j] * invN;
        float var = fmaxf(stats[D + j] * invN - mean * mean, 0.f);
        float a = g[j] * rsqrtf(var + 1e-5f);
        sa[j] = a;
        sb[j] = be[j] - mean * a;
    }
    __syncthreads();
    int i = blockIdx.x * blockDim.x + threadIdx.x;
    if (i >= total4) return;
    uint2 u = ((const uint2*)inh)[i];
    int c = (i * 4) & (D - 1);
    float d0 = bflo(u.x) * sa[c + 0] + sb[c + 0];
    float d1 = bfhi(u.x) * sa[c + 1] + sb[c + 1];
    float d2 = bflo(u.y) * sa[c + 2] + sb[c + 2];
    float d3 = bfhi(u.y) * sa[c + 3] + sb[c + 3];
    float o0 = d0 / (1.f + __expf(-d0));
    float o1 = d1 / (1.f + __expf(-d1));
    float o2 = d2 / (1.f + __expf(-d2));
    float o3 = d3 / (1.f + __expf(-d3));
    ((float4*)outp)[i] = make_float4(o0, o1, o2, o3);
}

extern "C" void kernel_launch(void* const* d_in, const int* in_sizes, int n_in,
                              void* d_out, int out_size, void* d_ws, size_t ws_size,
                              hipStream_t stream) {
    const float* x    = (const float*)d_in[0];
    const float* vals = (const float*)d_in[1];
    const float* W1   = (const float*)d_in[2];
    const float* b1   = (const float*)d_in[3];
    const float* g1   = (const float*)d_in[4];
    const float* be1  = (const float*)d_in[5];
    const float* W2   = (const float*)d_in[6];
    const float* b2   = (const float*)d_in[7];
    const float* g2   = (const float*)d_in[8];
    const float* be2  = (const float*)d_in[9];
    const float* eps  = (const float*)d_in[10];
    const int*  rows  = (const int*)d_in[11];
    const int*  cols  = (const int*)d_in[12];
    float* out = (float*)d_out;

    int N = in_sizes[0] / D;
    int E = in_sizes[1];
    int nb = (N + BR - 1) / BR;          // 782 buckets

    // ---- workspace layout ----
    char* p = (char*)d_ws;
    float* stats = (float*)p;              p += 4 * D * sizeof(float);   // stats1 | stats2
    int* gpart = (int*)p;                  p += (size_t)HB * NBMAX * sizeof(int);
    int* cbase = (int*)p;                  p += (size_t)(NBMAX + 1) * sizeof(int);
    int* ccur = (int*)p;                   p += (size_t)NBMAX * sizeof(int);
    p = (char*)(((uintptr_t)p + 15) & ~(uintptr_t)15);
    unsigned short* Wsw1 = (unsigned short*)p; p += (size_t)D * D * 2;
    unsigned short* Wsw2 = (unsigned short*)p; p += (size_t)D * D * 2;
    p = (char*)(((uintptr_t)p + 15) & ~(uintptr_t)15);
    uint2* sedge  = (uint2*)p;             p += (size_t)E * sizeof(uint2);
    unsigned* xh = (unsigned*)p;           p += (size_t)N * DH * sizeof(unsigned);  // also H1
    unsigned* aggh = (unsigned*)p;         /* N*DH uints; also H2 */

    float* stats1 = stats;
    float* stats2 = stats + 2 * D;

    int total4 = N * D / 4;
    int eb = (total4 + 255) / 256;
    int gblk = (N + 63) / 64;
    int chunk = (E + 255) / 256;
    float invN = 1.0f / (float)N;

    // 1. fused setup: xpack | hist partials | prepw
    k_setup<<<eb + HB + 16, 256, 0, stream>>>(x, xh, total4, rows, gpart, E,
                                              W1, W2, Wsw1, Wsw2, eb, nb);
    // 2. reduce+scan bucket counts; zero stats
    k_cscan<<<1, 1024, 0, stream>>>(gpart, cbase, ccur, stats, nb);
    // 3. coarse scatter
    k_cscatter<<<256, 256, 0, stream>>>(rows, cols, vals, ccur, sedge, E, nb, chunk);
    // 4. fused fine sort + gather (balanced: 782 blocks at 4 blocks/CU capacity)
    k_sortgather<<<nb, GT, 0, stream>>>(sedge, cbase, xh, eps, aggh, N);
    // 5. layer-1 GEMM (+stats1); H1 -> xh
    k_gemm<<<gblk, 256, 0, stream>>>((const unsigned short*)aggh, Wsw1, b1,
                                     (unsigned short*)xh, stats1, N);
    // 6. layer-2 GEMM with BN1+swish fused on A; H2 -> aggh (+stats2)
    k_gemm2f<<<gblk, 256, 0, stream>>>((const unsigned short*)xh, Wsw2, b2,
                                       stats1, g1, be1, invN,
                                       (unsigned short*)aggh, stats2, N);
    // 7. final BN+swish -> fp32 out
    k_bnswish<<<eb, 256, 0, stream>>>(aggh, out, stats2, g2, be2, invN, total4);
}